// Round 3
// baseline (1535.271 us; speedup 1.0000x reference)
//
#include <hip/hip_runtime.h>
#include <hip/hip_bf16.h>
#include <stdint.h>

#define LL 128
#define BB 64
#define VV 10000
#define EE 512
#define HH 512
#define G3 1536
#define MROWS 8192      // L*B
#define DM 8064         // (L-2)*B
#define D2H 1024
#define NPAD 10112      // 79*128

typedef __bf16 bf16x8 __attribute__((ext_vector_type(8)));
typedef float f32x4 __attribute__((ext_vector_type(4)));
typedef unsigned short u16;
typedef unsigned long long u64;
typedef u64 u64x2 __attribute__((ext_vector_type(2)));

static __device__ __forceinline__ float bf2f(u16 u) {
  unsigned int x = ((unsigned int)u) << 16;
  return __builtin_bit_cast(float, x);
}
static __device__ __forceinline__ u16 f2bf(float f) {
  unsigned int x = __builtin_bit_cast(unsigned int, f);
  unsigned int r = x + 0x7FFFu + ((x >> 16) & 1u);
  return (u16)(r >> 16);
}

// ---------------- cast kernels ----------------
__global__ void k_cast(const float4* __restrict__ src, ushort4* __restrict__ dst, int n4) {
  int i = blockIdx.x * blockDim.x + threadIdx.x;
  if (i < n4) {
    float4 v = src[i];
    ushort4 o;
    o.x = f2bf(v.x); o.y = f2bf(v.y); o.z = f2bf(v.z); o.w = f2bf(v.w);
    dst[i] = o;
  }
}

__global__ void k_cast_pad(const float* __restrict__ src, u16* __restrict__ dst) {
  int i = blockIdx.x * 256 + threadIdx.x;     // over NPAD*1024/4
  int row = i >> 8;
  int c4 = (i & 255) * 4;
  if (row >= NPAD) return;
  ushort4 o;
  if (row < VV) {
    float4 v = *(const float4*)(src + (long)row * 1024 + c4);
    o.x = f2bf(v.x); o.y = f2bf(v.y); o.z = f2bf(v.z); o.w = f2bf(v.w);
  } else {
    o.x = 0; o.y = 0; o.z = 0; o.w = 0;
  }
  *(ushort4*)(dst + (long)row * 1024 + c4) = o;
}

__global__ void k_embed(const int* __restrict__ seq, const float* __restrict__ emb,
                        u16* __restrict__ x) {
  int rb = blockIdx.x;              // l*64+b
  int v = seq[rb];
  const float4* s = (const float4*)(emb + (long)v * EE);
  ushort4* d = (ushort4*)(x + (long)rb * EE);
  int t = threadIdx.x;              // 128 threads, one float4 each
  float4 val = s[t];
  ushort4 o;
  o.x = f2bf(val.x); o.y = f2bf(val.y); o.z = f2bf(val.z); o.w = f2bf(val.w);
  d[t] = o;
}

// ---------------- GEMM: C[M,N] = A[M,K] * B[N,K]^T + bias ----------------
// A,B bf16 row-major (K contiguous). OUTF32: 1 -> f32 store (decoder), 0 -> bf16 store (gx).
template<int OUTF32>
__global__ __launch_bounds__(256) void k_gemm(
    const u16* __restrict__ A, const u16* __restrict__ B,
    const float* __restrict__ bias, void* __restrict__ C,
    int lda, int ldb, int ldc, int K, int ncols)
{
  __shared__ char smem[32768];      // A tile 16KB + B tile 16KB, swizzled
  const int tid = threadIdx.x;
  const int l = tid & 63;
  const int w = tid >> 6;
  const int wr = w >> 1, wc = w & 1;
  const long tM = (long)blockIdx.x * 128;
  const long tN = (long)blockIdx.y * 128;

  f32x4 acc[4][4];
#pragma unroll
  for (int m = 0; m < 4; m++)
#pragma unroll
    for (int n = 0; n < 4; n++) acc[m][n] = {0.f, 0.f, 0.f, 0.f};

  const int nk = K >> 6;
  for (int kt = 0; kt < nk; ++kt) {
    const int k0 = kt << 6;
    // stage A and B tiles: 1024 chunks of 16B each per tile, 4 per thread
#pragma unroll
    for (int t = 0; t < 4; t++) {
      int c2 = t * 256 + tid;
      int row = c2 >> 3, k8 = c2 & 7;
      uint4 va = *(const uint4*)(A + (tM + row) * lda + k0 + k8 * 8);
      int off = row * 128 + ((k8 * 16) ^ ((row & 7) << 4));
      *(uint4*)(smem + off) = va;
      uint4 vb = *(const uint4*)(B + (tN + row) * ldb + k0 + k8 * 8);
      *(uint4*)(smem + 16384 + off) = vb;
    }
    __syncthreads();
#pragma unroll
    for (int kk = 0; kk < 2; kk++) {
      const int kb = kk * 64 + ((l >> 4) * 16);
      bf16x8 af[4], bfr[4];
#pragma unroll
      for (int m = 0; m < 4; m++) {
        int ra = wr * 64 + m * 16 + (l & 15);
        af[m] = *(const bf16x8*)(smem + ra * 128 + (kb ^ ((l & 7) << 4)));
      }
#pragma unroll
      for (int n = 0; n < 4; n++) {
        int rb2 = wc * 64 + n * 16 + (l & 15);
        bfr[n] = *(const bf16x8*)(smem + 16384 + rb2 * 128 + (kb ^ ((l & 7) << 4)));
      }
#pragma unroll
      for (int m = 0; m < 4; m++)
#pragma unroll
        for (int n = 0; n < 4; n++)
          acc[m][n] = __builtin_amdgcn_mfma_f32_16x16x32_bf16(af[m], bfr[n], acc[m][n], 0, 0, 0);
    }
    __syncthreads();
  }
  // epilogue
#pragma unroll
  for (int n = 0; n < 4; n++) {
    long col = tN + wc * 64 + n * 16 + (l & 15);
    float bv = (col < ncols) ? bias[col] : 0.f;
    if (col < ncols) {
#pragma unroll
      for (int m = 0; m < 4; m++) {
        long row = tM + wr * 64 + m * 16 + ((l >> 4) * 4);
#pragma unroll
        for (int r = 0; r < 4; r++) {
          float v = acc[m][n][r] + bv;
          if (OUTF32) ((float*)C)[(row + r) * ldc + col] = v;
          else        ((u16*)C)[(row + r) * ldc + col] = f2bf(v);
        }
      }
    }
  }
}

// ---------------- GRU recurrence ----------------
// grid (16, 2): 16 hidden-slice blocks per direction. Each block owns hidden
// indices [blk*32, blk*32+32) -> W_hh rows {g*512 + blk*32 + j} resident in LDS.
// Cross-block h exchange: agent-scope RELAXED atomics (bypass non-coherent
// L1/L2, served at the shared coherence point) + per-step counter flags.
// No acquire/release fences -> no cache-wide invalidate/writeback per step.
__global__ __launch_bounds__(256) void k_gru(
    const u16* __restrict__ Whh_all,   // [2][1536][512] bf16
    const float* __restrict__ bhh_f, const float* __restrict__ bhh_b,
    const u16* __restrict__ gx_all,    // [2][8192][1536] bf16
    u16* __restrict__ hbuf,            // [2][2][64][512] bf16
    u16* __restrict__ cat,             // [8064][1024] bf16
    int* __restrict__ bar)             // [2][128]
{
  const int blk = blockIdx.x;
  const int dir = blockIdx.y;
  const int tid = threadIdx.x;
  const int l = tid & 63, w = tid >> 6;
  const u16* Whh = Whh_all + (long)dir * G3 * HH;
  const float* bhh = dir ? bhh_b : bhh_f;
  const u16* gx = gx_all + (long)dir * MROWS * G3;
  u16* hb = hbuf + (long)dir * 2 * BB * HH;
  int* bars = bar + dir * LL;

  __shared__ char Wl[96 * 1024];   // 96 rows x 512 bf16, swizzled

  // stage W slice once: 6144 chunks of 8 bf16
  for (int c = tid; c < 6144; c += 256) {
    int lr = c >> 6;          // 64 chunks per row
    int k8 = c & 63;
    int gr = (lr >> 5) * HH + blk * 32 + (lr & 31);
    uint4 v = *(const uint4*)(Whh + (long)gr * HH + k8 * 8);
    *(uint4*)(Wl + lr * 1024 + ((k8 * 16) ^ ((lr & 7) << 4))) = v;
  }
  float bh[6];
#pragma unroll
  for (int n = 0; n < 6; n++) {
    int c = n * 16 + (l & 15);
    bh[n] = bhh[(c >> 5) * HH + blk * 32 + (c & 31)];
  }
  float hreg[4][2] = {};
  __syncthreads();

  // gx fragment loader (plain loads; gx written by a prior kernel)
  u16 gxv[3][4][2];
  const int lrow = w * 16 + ((l >> 4) * 4);   // batch base for this thread's rows
  auto load_gx = [&](int lpos) {
#pragma unroll
    for (int r = 0; r < 4; r++) {
      const u16* gxr = gx + ((long)lpos * BB + (lrow + r)) * G3 + blk * 32;
#pragma unroll
      for (int g = 0; g < 3; g++)
#pragma unroll
        for (int p = 0; p < 2; p++)
          gxv[g][r][p] = gxr[g * HH + p * 16 + (l & 15)];
    }
  };
  load_gx(dir ? (LL - 1) : 0);

  for (int t = 0; t < LL; ++t) {
    const int lpos = dir ? (LL - 1 - t) : t;
    const int par = t & 1;
    const u16* hsrc = hb + par * BB * HH;

    // A fragments: h rows (batch) for this wave — agent-coherent atomic loads
    bf16x8 af[16];
    {
      const u16* hrow = hsrc + (w * 16 + (l & 15)) * HH + ((l >> 4) * 8);
#pragma unroll
      for (int kc = 0; kc < 16; kc++) {
        const u64* q = (const u64*)(hrow + kc * 32);
        u64x2 d;
        d.x = __hip_atomic_load(q,     __ATOMIC_RELAXED, __HIP_MEMORY_SCOPE_AGENT);
        d.y = __hip_atomic_load(q + 1, __ATOMIC_RELAXED, __HIP_MEMORY_SCOPE_AGENT);
        af[kc] = __builtin_bit_cast(bf16x8, d);
      }
    }
    // MFMA: gh[64 x 96]
    f32x4 acc[6];
#pragma unroll
    for (int n = 0; n < 6; n++) acc[n] = {0.f, 0.f, 0.f, 0.f};
#pragma unroll
    for (int kc = 0; kc < 16; kc++) {
      const int kb = kc * 64 + ((l >> 4) * 16);
#pragma unroll
      for (int n = 0; n < 6; n++) {
        int lr = n * 16 + (l & 15);
        bf16x8 bfr = *(const bf16x8*)(Wl + lr * 1024 + (kb ^ ((l & 7) << 4)));
        acc[n] = __builtin_amdgcn_mfma_f32_16x16x32_bf16(af[kc], bfr, acc[n], 0, 0, 0);
      }
    }
    // gates + writes
    u16* hdst = hb + (par ^ 1) * BB * HH;
#pragma unroll
    for (int r = 0; r < 4; r++) {
      int batch = lrow + r;
#pragma unroll
      for (int p = 0; p < 2; p++) {
        float ghr = acc[0 + p][r] + bh[0 + p];
        float ghz = acc[2 + p][r] + bh[2 + p];
        float ghn = acc[4 + p][r] + bh[4 + p];
        float xr = bf2f(gxv[0][r][p]);
        float xz = bf2f(gxv[1][r][p]);
        float xn = bf2f(gxv[2][r][p]);
        float ar = fminf(fmaxf(xr + ghr, -30.f), 30.f);
        float az = fminf(fmaxf(xz + ghz, -30.f), 30.f);
        float rg = 1.f / (1.f + __expf(-ar));
        float zg = 1.f / (1.f + __expf(-az));
        float an = fminf(fmaxf(xn + rg * ghn, -30.f), 30.f);
        float e2 = __expf(-2.f * an);
        float ng = (1.f - e2) / (1.f + e2);
        float hn = (1.f - zg) * ng + zg * hreg[r][p];
        hreg[r][p] = hn;
        u16 h16 = f2bf(hn);
        int j = blk * 32 + p * 16 + (l & 15);
        // write-through (agent-scope atomic) so vmcnt-ack == visible at L3
        __hip_atomic_store(&hdst[batch * HH + j], h16, __ATOMIC_RELAXED, __HIP_MEMORY_SCOPE_AGENT);
        if (dir == 0) {
          if (lpos < LL - 2) cat[((long)lpos * BB + batch) * D2H + j] = h16;
        } else {
          if (lpos >= 2) cat[((long)(lpos - 2) * BB + batch) * D2H + HH + j] = h16;
        }
      }
    }
    if (t < LL - 1) {
      // drain this wave's stores to the coherence point, then block-wide meet
      asm volatile("s_waitcnt vmcnt(0)" ::: "memory");
      __syncthreads();
      if (tid == 0)
        __hip_atomic_fetch_add(&bars[t], 1, __ATOMIC_RELAXED, __HIP_MEMORY_SCOPE_AGENT);
      // prefetch next step's gx while other blocks finish
      load_gx(dir ? (LL - 2 - t) : (t + 1));
      if (tid == 0) {
        while (__hip_atomic_load(&bars[t], __ATOMIC_RELAXED, __HIP_MEMORY_SCOPE_AGENT) < 16)
          __builtin_amdgcn_s_sleep(1);
      }
      __syncthreads();
      asm volatile("" ::: "memory");   // keep next-iter h loads below the spin
    }
  }
}

// ---------------- log-softmax over V=10000 per row ----------------
__global__ __launch_bounds__(256) void k_lsm(float* __restrict__ out) {
  const long row = blockIdx.x;
  float* p = out + row * VV;
  const int tid = threadIdx.x;
  const int l = tid & 63, w = tid >> 6;
  __shared__ float red[8];

  float4 v[10];
  float m = -1e30f;
#pragma unroll
  for (int j = 0; j < 10; j++) {
    int idx = j * 256 + tid;
    if (idx < 2500) {
      v[j] = *(float4*)(p + idx * 4);
      m = fmaxf(m, fmaxf(fmaxf(v[j].x, v[j].y), fmaxf(v[j].z, v[j].w)));
    }
  }
#pragma unroll
  for (int off = 32; off; off >>= 1) m = fmaxf(m, __shfl_xor(m, off));
  if (l == 0) red[w] = m;
  __syncthreads();
  m = fmaxf(fmaxf(red[0], red[1]), fmaxf(red[2], red[3]));

  float s = 0.f;
#pragma unroll
  for (int j = 0; j < 10; j++) {
    int idx = j * 256 + tid;
    if (idx < 2500) {
      s += __expf(v[j].x - m) + __expf(v[j].y - m) + __expf(v[j].z - m) + __expf(v[j].w - m);
    }
  }
#pragma unroll
  for (int off = 32; off; off >>= 1) s += __shfl_xor(s, off);
  if (l == 0) red[4 + w] = s;
  __syncthreads();
  s = red[4] + red[5] + red[6] + red[7];
  float lse = m + logf(s);

#pragma unroll
  for (int j = 0; j < 10; j++) {
    int idx = j * 256 + tid;
    if (idx < 2500) {
      float4 o;
      o.x = v[j].x - lse; o.y = v[j].y - lse; o.z = v[j].z - lse; o.w = v[j].w - lse;
      *(float4*)(p + idx * 4) = o;
    }
  }
}

// ---------------- launch ----------------
extern "C" void kernel_launch(void* const* d_in, const int* in_sizes, int n_in,
                              void* d_out, int out_size, void* d_ws, size_t ws_size,
                              hipStream_t stream) {
  const int*   seq  = (const int*)d_in[0];
  const float* emb  = (const float*)d_in[2];
  const float* Wihf = (const float*)d_in[3];
  const float* Whhf = (const float*)d_in[4];
  const float* bihf = (const float*)d_in[5];
  const float* bhhf = (const float*)d_in[6];
  const float* Wihb = (const float*)d_in[7];
  const float* Whhb = (const float*)d_in[8];
  const float* bihb = (const float*)d_in[9];
  const float* bhhb = (const float*)d_in[10];
  const float* decW = (const float*)d_in[11];
  const float* decb = (const float*)d_in[12];

  char* ws = (char*)d_ws;
  size_t off = 0;
  u16* Whh_bf = (u16*)(ws + off); off += (size_t)2 * G3 * HH * 2;        // 3,145,728
  u16* Wih_bf = (u16*)(ws + off); off += (size_t)2 * G3 * EE * 2;        // 3,145,728
  u16* decW_bf = (u16*)(ws + off); off += (size_t)NPAD * D2H * 2;        // 20,709,376
  u16* xb = (u16*)(ws + off); off += (size_t)MROWS * EE * 2;             // 8,388,608
  u16* gxb = (u16*)(ws + off); off += (size_t)2 * MROWS * G3 * 2;        // 50,331,648
  u16* cat = (u16*)(ws + off); off += (size_t)DM * D2H * 2;              // 16,515,072
  u16* hbuf = (u16*)(ws + off); off += (size_t)2 * 2 * BB * HH * 2;      // 262,144
  int* bar = (int*)(ws + off); off += 2 * LL * 4;                        // 1,024

  // zero h-state + barriers (contiguous) — re-run every call so barriers reset
  (void)hipMemsetAsync(hbuf, 0, (size_t)2 * 2 * BB * HH * 2 + 2 * LL * 4, stream);

  const int n4w = G3 * HH / 4;   // 196608
  k_cast<<<(n4w + 255) / 256, 256, 0, stream>>>((const float4*)Whhf, (ushort4*)(Whh_bf), n4w);
  k_cast<<<(n4w + 255) / 256, 256, 0, stream>>>((const float4*)Whhb, (ushort4*)(Whh_bf + G3 * HH), n4w);
  k_cast<<<(n4w + 255) / 256, 256, 0, stream>>>((const float4*)Wihf, (ushort4*)(Wih_bf), n4w);
  k_cast<<<(n4w + 255) / 256, 256, 0, stream>>>((const float4*)Wihb, (ushort4*)(Wih_bf + G3 * EE), n4w);
  k_cast_pad<<<NPAD, 256, 0, stream>>>(decW, decW_bf);
  k_embed<<<MROWS, 128, 0, stream>>>(seq, emb, xb);

  // gx GEMMs: [8192,1536] = x[8192,512] @ W_ih^T + b_ih
  k_gemm<0><<<dim3(64, 12), 256, 0, stream>>>(xb, Wih_bf, bihf, gxb, EE, EE, G3, EE, G3);
  k_gemm<0><<<dim3(64, 12), 256, 0, stream>>>(xb, Wih_bf + G3 * EE, bihb, gxb + (size_t)MROWS * G3, EE, EE, G3, EE, G3);

  // recurrence
  k_gru<<<dim3(16, 2), 256, 0, stream>>>(Whh_bf, bhhf, bhhb, gxb, hbuf, cat, bar);

  // decoder: [8064,10000] = cat[8064,1024] @ decW^T + decb  (f32 into d_out)
  k_gemm<1><<<dim3(63, 79), 256, 0, stream>>>(cat, decW_bf, decb, d_out, D2H, D2H, VV, D2H, VV);

  // log-softmax in place
  k_lsm<<<DM, 256, 0, stream>>>((float*)d_out);
}

// Round 5
// 1315.742 us; speedup vs baseline: 1.1668x; 1.1668x over previous
//
#include <hip/hip_runtime.h>
#include <hip/hip_bf16.h>
#include <stdint.h>

#define LL 128
#define BB 64
#define VV 10000
#define EE 512
#define HH 512
#define G3 1536
#define MROWS 8192      // L*B
#define DM 8064         // (L-2)*B
#define D2H 1024
#define NPAD 10112      // 79*128

typedef __bf16 bf16x8 __attribute__((ext_vector_type(8)));
typedef float f32x4 __attribute__((ext_vector_type(4)));
typedef unsigned int u32x4 __attribute__((ext_vector_type(4)));
typedef unsigned short u16;

static __device__ __forceinline__ float bf2f(u16 u) {
  unsigned int x = ((unsigned int)u) << 16;
  return __builtin_bit_cast(float, x);
}
static __device__ __forceinline__ u16 f2bf(float f) {
  unsigned int x = __builtin_bit_cast(unsigned int, f);
  unsigned int r = x + 0x7FFFu + ((x >> 16) & 1u);
  return (u16)(r >> 16);
}

// coherent (cache-bypassing) 16B load/store — plain VMEM pipe, not atomics
static __device__ __forceinline__ u32x4 cload16(const void* p) {
  u32x4 v;
  asm volatile("global_load_dwordx4 %0, %1, off sc0 sc1" : "=v"(v) : "v"(p));
  return v;
}
static __device__ __forceinline__ void cstore16(void* p, u32x4 v) {
  asm volatile("global_store_dwordx4 %0, %1, off sc0 sc1" :: "v"(p), "v"(v) : "memory");
}

// ---------------- cast kernels ----------------
__global__ void k_cast(const float4* __restrict__ src, ushort4* __restrict__ dst, int n4) {
  int i = blockIdx.x * blockDim.x + threadIdx.x;
  if (i < n4) {
    float4 v = src[i];
    ushort4 o;
    o.x = f2bf(v.x); o.y = f2bf(v.y); o.z = f2bf(v.z); o.w = f2bf(v.w);
    dst[i] = o;
  }
}

__global__ void k_cast_pad(const float* __restrict__ src, u16* __restrict__ dst) {
  int i = blockIdx.x * 256 + threadIdx.x;     // over NPAD*1024/4
  int row = i >> 8;
  int c4 = (i & 255) * 4;
  if (row >= NPAD) return;
  ushort4 o;
  if (row < VV) {
    float4 v = *(const float4*)(src + (long)row * 1024 + c4);
    o.x = f2bf(v.x); o.y = f2bf(v.y); o.z = f2bf(v.z); o.w = f2bf(v.w);
  } else {
    o.x = 0; o.y = 0; o.z = 0; o.w = 0;
  }
  *(ushort4*)(dst + (long)row * 1024 + c4) = o;
}

__global__ void k_embed(const int* __restrict__ seq, const float* __restrict__ emb,
                        u16* __restrict__ x) {
  int rb = blockIdx.x;              // l*64+b
  int v = seq[rb];
  const float4* s = (const float4*)(emb + (long)v * EE);
  ushort4* d = (ushort4*)(x + (long)rb * EE);
  int t = threadIdx.x;              // 128 threads, one float4 each
  float4 val = s[t];
  ushort4 o;
  o.x = f2bf(val.x); o.y = f2bf(val.y); o.z = f2bf(val.z); o.w = f2bf(val.w);
  d[t] = o;
}

// ---------------- GEMM: C[M,N] = A[M,K] * B[N,K]^T + bias ----------------
template<int OUTF32>
__global__ __launch_bounds__(256) void k_gemm(
    const u16* __restrict__ A, const u16* __restrict__ B,
    const float* __restrict__ bias, void* __restrict__ C,
    int lda, int ldb, int ldc, int K, int ncols)
{
  __shared__ char smem[32768];      // A tile 16KB + B tile 16KB, swizzled
  const int tid = threadIdx.x;
  const int l = tid & 63;
  const int w = tid >> 6;
  const int wr = w >> 1, wc = w & 1;
  const long tM = (long)blockIdx.x * 128;
  const long tN = (long)blockIdx.y * 128;

  f32x4 acc[4][4];
#pragma unroll
  for (int m = 0; m < 4; m++)
#pragma unroll
    for (int n = 0; n < 4; n++) acc[m][n] = {0.f, 0.f, 0.f, 0.f};

  const int nk = K >> 6;
  for (int kt = 0; kt < nk; ++kt) {
    const int k0 = kt << 6;
#pragma unroll
    for (int t = 0; t < 4; t++) {
      int c2 = t * 256 + tid;
      int row = c2 >> 3, k8 = c2 & 7;
      uint4 va = *(const uint4*)(A + (tM + row) * lda + k0 + k8 * 8);
      int off = row * 128 + ((k8 * 16) ^ ((row & 7) << 4));
      *(uint4*)(smem + off) = va;
      uint4 vb = *(const uint4*)(B + (tN + row) * ldb + k0 + k8 * 8);
      *(uint4*)(smem + 16384 + off) = vb;
    }
    __syncthreads();
#pragma unroll
    for (int kk = 0; kk < 2; kk++) {
      const int kb = kk * 64 + ((l >> 4) * 16);
      bf16x8 af[4], bfr[4];
#pragma unroll
      for (int m = 0; m < 4; m++) {
        int ra = wr * 64 + m * 16 + (l & 15);
        af[m] = *(const bf16x8*)(smem + ra * 128 + (kb ^ ((l & 7) << 4)));
      }
#pragma unroll
      for (int n = 0; n < 4; n++) {
        int rb2 = wc * 64 + n * 16 + (l & 15);
        bfr[n] = *(const bf16x8*)(smem + 16384 + rb2 * 128 + (kb ^ ((l & 7) << 4)));
      }
#pragma unroll
      for (int m = 0; m < 4; m++)
#pragma unroll
        for (int n = 0; n < 4; n++)
          acc[m][n] = __builtin_amdgcn_mfma_f32_16x16x32_bf16(af[m], bfr[n], acc[m][n], 0, 0, 0);
    }
    __syncthreads();
  }
#pragma unroll
  for (int n = 0; n < 4; n++) {
    long col = tN + wc * 64 + n * 16 + (l & 15);
    float bv = (col < ncols) ? bias[col] : 0.f;
    if (col < ncols) {
#pragma unroll
      for (int m = 0; m < 4; m++) {
        long row = tM + wr * 64 + m * 16 + ((l >> 4) * 4);
#pragma unroll
        for (int r = 0; r < 4; r++) {
          float v = acc[m][n][r] + bv;
          if (OUTF32) ((float*)C)[(row + r) * ldc + col] = v;
          else        ((u16*)C)[(row + r) * ldc + col] = f2bf(v);
        }
      }
    }
  }
}

// ---------------- GRU recurrence ----------------
// grid (16, 2): block owns hidden cols [blk*32, blk*32+32); W_hh slice in LDS.
// Per-step cross-block h exchange: LDS-repacked 16B coherent stores + per-block
// flag words + wide-poll. No atomics on the data path.
__global__ __launch_bounds__(256) void k_gru(
    const u16* __restrict__ Whh_all,   // [2][1536][512] bf16
    const float* __restrict__ bhh_f, const float* __restrict__ bhh_b,
    const u16* __restrict__ gx_all,    // [2][8192][1536] bf16
    u16* __restrict__ hbuf,            // [2][2][64][512] bf16
    u16* __restrict__ cat,             // [8064][1024] bf16
    int* __restrict__ bar16)           // [2][128][16]
{
  const int blk = blockIdx.x;
  const int dir = blockIdx.y;
  const int tid = threadIdx.x;
  const int l = tid & 63, w = tid >> 6;
  const u16* Whh = Whh_all + (long)dir * G3 * HH;
  const float* bhh = dir ? bhh_b : bhh_f;
  const u16* gx = gx_all + (long)dir * MROWS * G3;
  u16* hb = hbuf + (long)dir * 2 * BB * HH;

  __shared__ char Wl[96 * 1024];               // 96 rows x 512 bf16, swizzled
  __shared__ __align__(16) u16 hstage[BB][32]; // 4KB repack tile

  // stage W slice once
  for (int c = tid; c < 6144; c += 256) {
    int lr = c >> 6;
    int k8 = c & 63;
    int gr = (lr >> 5) * HH + blk * 32 + (lr & 31);
    uint4 v = *(const uint4*)(Whh + (long)gr * HH + k8 * 8);
    *(uint4*)(Wl + lr * 1024 + ((k8 * 16) ^ ((lr & 7) << 4))) = v;
  }
  float bh[6];
#pragma unroll
  for (int n = 0; n < 6; n++) {
    int c = n * 16 + (l & 15);
    bh[n] = bhh[(c >> 5) * HH + blk * 32 + (c & 31)];
  }
  float hreg[4][2] = {};
  __syncthreads();

  // gx prefetch (plain loads; gx written by a prior kernel)
  u16 gxv[3][4][2];
  const int lrow = w * 16 + ((l >> 4) * 4);
  auto load_gx = [&](int lpos) {
#pragma unroll
    for (int r = 0; r < 4; r++) {
      const u16* gxr = gx + ((long)lpos * BB + (lrow + r)) * G3 + blk * 32;
#pragma unroll
      for (int g = 0; g < 3; g++)
#pragma unroll
        for (int p = 0; p < 2; p++)
          gxv[g][r][p] = gxr[g * HH + p * 16 + (l & 15)];
    }
  };
  load_gx(dir ? (LL - 1) : 0);

  const int srow = tid >> 2;          // repack read: batch row
  const int schunk = tid & 3;         // 16B chunk within 32 cols

  for (int t = 0; t < LL; ++t) {
    const int lpos = dir ? (LL - 1 - t) : t;
    const int par = t & 1;
    const u16* hsrc = hb + par * BB * HH;

    // ---- h tile load: 16 coherent 16B vector loads ----
    bf16x8 af[16];
    {
      const u16* hrow = hsrc + (w * 16 + (l & 15)) * HH + ((l >> 4) * 8);
#pragma unroll
      for (int kc = 0; kc < 16; kc++) {
        u32x4 tmp = cload16(hrow + kc * 32);
        af[kc] = __builtin_bit_cast(bf16x8, tmp);
      }
    }
    asm volatile("s_waitcnt vmcnt(0)" ::: "memory");
    __builtin_amdgcn_sched_barrier(0);

    // ---- MFMA: gh[64 x 96] ----
    f32x4 acc[6];
#pragma unroll
    for (int n = 0; n < 6; n++) acc[n] = {0.f, 0.f, 0.f, 0.f};
#pragma unroll
    for (int kc = 0; kc < 16; kc++) {
      const int kb = kc * 64 + ((l >> 4) * 16);
#pragma unroll
      for (int n = 0; n < 6; n++) {
        int lr = n * 16 + (l & 15);
        bf16x8 bfr = *(const bf16x8*)(Wl + lr * 1024 + (kb ^ ((l & 7) << 4)));
        acc[n] = __builtin_amdgcn_mfma_f32_16x16x32_bf16(af[kc], bfr, acc[n], 0, 0, 0);
      }
    }

    // ---- gates -> hstage (LDS repack) ----
    __syncthreads();   // protect hstage reuse across iterations
#pragma unroll
    for (int r = 0; r < 4; r++) {
#pragma unroll
      for (int p = 0; p < 2; p++) {
        float ghr = acc[0 + p][r] + bh[0 + p];
        float ghz = acc[2 + p][r] + bh[2 + p];
        float ghn = acc[4 + p][r] + bh[4 + p];
        float xr = bf2f(gxv[0][r][p]);
        float xz = bf2f(gxv[1][r][p]);
        float xn = bf2f(gxv[2][r][p]);
        float ar = fminf(fmaxf(xr + ghr, -30.f), 30.f);
        float az = fminf(fmaxf(xz + ghz, -30.f), 30.f);
        float rg = 1.f / (1.f + __expf(-ar));
        float zg = 1.f / (1.f + __expf(-az));
        float an = fminf(fmaxf(xn + rg * ghn, -30.f), 30.f);
        float e2 = __expf(-2.f * an);
        float ng = (1.f - e2) / (1.f + e2);
        float hn = (1.f - zg) * ng + zg * hreg[r][p];
        hreg[r][p] = hn;
        hstage[lrow + r][p * 16 + (l & 15)] = f2bf(hn);
      }
    }
    __syncthreads();

    // ---- wide h store (coherent) + flag + overlapped cat store/prefetch ----
    u32x4 hv = *(const u32x4*)&hstage[srow][schunk * 8];
    if (t < LL - 1) {
      u16* hdst = hb + (par ^ 1) * BB * HH;
      cstore16(hdst + srow * HH + blk * 32 + schunk * 8, hv);
      asm volatile("s_waitcnt vmcnt(0)" ::: "memory");
      __syncthreads();   // all threads' stores drained to coherence point
      if (tid == 0)
        __hip_atomic_store(&bar16[(dir * LL + t) * 16 + blk], 1,
                           __ATOMIC_RELAXED, __HIP_MEMORY_SCOPE_AGENT);
    }
    // cat store (plain; consumed by next kernel)
    if (dir == 0) {
      if (lpos < LL - 2)
        *(u32x4*)(cat + ((long)lpos * BB + srow) * D2H + blk * 32 + schunk * 8) = hv;
    } else {
      if (lpos >= 2)
        *(u32x4*)(cat + ((long)(lpos - 2) * BB + srow) * D2H + HH + blk * 32 + schunk * 8) = hv;
    }
    if (t < LL - 1) {
      load_gx(dir ? (LL - 2 - t) : (t + 1));   // overlap with poll
      // poll all 16 producer flags (16 lanes, one word each)
      const int* flg = bar16 + (dir * LL + t) * 16;
      for (;;) {
        int v = 1;
        if (l < 16)
          v = __hip_atomic_load(&flg[l], __ATOMIC_RELAXED, __HIP_MEMORY_SCOPE_AGENT);
        if (__all(v != 0)) break;
      }
      __syncthreads();
      asm volatile("" ::: "memory");
    }
  }
}

// ---------------- log-softmax over V=10000 per row ----------------
__global__ __launch_bounds__(256) void k_lsm(float* __restrict__ out) {
  const long row = blockIdx.x;
  float* p = out + row * VV;
  const int tid = threadIdx.x;
  const int l = tid & 63, w = tid >> 6;
  __shared__ float red[8];

  float4 v[10];
  float m = -1e30f;
#pragma unroll
  for (int j = 0; j < 10; j++) {
    int idx = j * 256 + tid;
    if (idx < 2500) {
      v[j] = *(float4*)(p + idx * 4);
      m = fmaxf(m, fmaxf(fmaxf(v[j].x, v[j].y), fmaxf(v[j].z, v[j].w)));
    }
  }
#pragma unroll
  for (int off = 32; off; off >>= 1) m = fmaxf(m, __shfl_xor(m, off));
  if (l == 0) red[w] = m;
  __syncthreads();
  m = fmaxf(fmaxf(red[0], red[1]), fmaxf(red[2], red[3]));

  float s = 0.f;
#pragma unroll
  for (int j = 0; j < 10; j++) {
    int idx = j * 256 + tid;
    if (idx < 2500) {
      s += __expf(v[j].x - m) + __expf(v[j].y - m) + __expf(v[j].z - m) + __expf(v[j].w - m);
    }
  }
#pragma unroll
  for (int off = 32; off; off >>= 1) s += __shfl_xor(s, off);
  if (l == 0) red[4 + w] = s;
  __syncthreads();
  s = red[4] + red[5] + red[6] + red[7];
  float lse = m + logf(s);

#pragma unroll
  for (int j = 0; j < 10; j++) {
    int idx = j * 256 + tid;
    if (idx < 2500) {
      float4 o;
      o.x = v[j].x - lse; o.y = v[j].y - lse; o.z = v[j].z - lse; o.w = v[j].w - lse;
      *(float4*)(p + idx * 4) = o;
    }
  }
}

// ---------------- launch ----------------
extern "C" void kernel_launch(void* const* d_in, const int* in_sizes, int n_in,
                              void* d_out, int out_size, void* d_ws, size_t ws_size,
                              hipStream_t stream) {
  const int*   seq  = (const int*)d_in[0];
  const float* emb  = (const float*)d_in[2];
  const float* Wihf = (const float*)d_in[3];
  const float* Whhf = (const float*)d_in[4];
  const float* bihf = (const float*)d_in[5];
  const float* bhhf = (const float*)d_in[6];
  const float* Wihb = (const float*)d_in[7];
  const float* Whhb = (const float*)d_in[8];
  const float* bihb = (const float*)d_in[9];
  const float* bhhb = (const float*)d_in[10];
  const float* decW = (const float*)d_in[11];
  const float* decb = (const float*)d_in[12];

  char* ws = (char*)d_ws;
  size_t off = 0;
  u16* Whh_bf = (u16*)(ws + off); off += (size_t)2 * G3 * HH * 2;
  u16* Wih_bf = (u16*)(ws + off); off += (size_t)2 * G3 * EE * 2;
  u16* decW_bf = (u16*)(ws + off); off += (size_t)NPAD * D2H * 2;
  u16* xb = (u16*)(ws + off); off += (size_t)MROWS * EE * 2;
  u16* gxb = (u16*)(ws + off); off += (size_t)2 * MROWS * G3 * 2;
  u16* cat = (u16*)(ws + off); off += (size_t)DM * D2H * 2;
  u16* hbuf = (u16*)(ws + off); off += (size_t)2 * 2 * BB * HH * 2;      // 262,144
  int* bar16 = (int*)(ws + off); off += (size_t)2 * LL * 16 * 4;         // 16,384

  // zero h-state + flags (contiguous) — re-run every call so flags reset
  (void)hipMemsetAsync(hbuf, 0, (size_t)2 * 2 * BB * HH * 2 + (size_t)2 * LL * 16 * 4, stream);

  const int n4w = G3 * HH / 4;
  k_cast<<<(n4w + 255) / 256, 256, 0, stream>>>((const float4*)Whhf, (ushort4*)(Whh_bf), n4w);
  k_cast<<<(n4w + 255) / 256, 256, 0, stream>>>((const float4*)Whhb, (ushort4*)(Whh_bf + G3 * HH), n4w);
  k_cast<<<(n4w + 255) / 256, 256, 0, stream>>>((const float4*)Wihf, (ushort4*)(Wih_bf), n4w);
  k_cast<<<(n4w + 255) / 256, 256, 0, stream>>>((const float4*)Wihb, (ushort4*)(Wih_bf + G3 * EE), n4w);
  k_cast_pad<<<NPAD, 256, 0, stream>>>(decW, decW_bf);
  k_embed<<<MROWS, 128, 0, stream>>>(seq, emb, xb);

  k_gemm<0><<<dim3(64, 12), 256, 0, stream>>>(xb, Wih_bf, bihf, gxb, EE, EE, G3, EE, G3);
  k_gemm<0><<<dim3(64, 12), 256, 0, stream>>>(xb, Wih_bf + G3 * EE, bihb, gxb + (size_t)MROWS * G3, EE, EE, G3, EE, G3);

  k_gru<<<dim3(16, 2), 256, 0, stream>>>(Whh_bf, bhhf, bhhb, gxb, hbuf, cat, bar16);

  k_gemm<1><<<dim3(63, 79), 256, 0, stream>>>(cat, decW_bf, decb, d_out, D2H, D2H, VV, D2H, VV);

  k_lsm<<<DM, 256, 0, stream>>>((float*)d_out);
}